// Round 3
// baseline (1028.227 us; speedup 1.0000x reference)
//
#include <hip/hip_runtime.h>
#include <hip/hip_fp16.h>
#include <stdint.h>

#define NN 100000
#define NE 1600000
#define NG 1000
#define LDA 112   // fp32 row stride for h (pooling input): 448 B
#define LDX 128   // half row stride for fp16 activation tables: 256 B

typedef float f32x4 __attribute__((ext_vector_type(4)));
typedef _Float16 f16x8 __attribute__((ext_vector_type(8)));

// ---------------- degree ----------------
__global__ void k_deg(const int* __restrict__ col, int* __restrict__ degcnt) {
    int e = blockIdx.x * 256 + threadIdx.x;
    if (e < NE) atomicAdd(&degcnt[col[e]], 1);
}

// ---------------- prefix scans for CSR ----------------
__global__ void k_scan1(const int* __restrict__ cnt, int* __restrict__ csum) {
    __shared__ int s[256];
    int i = blockIdx.x * 256 + threadIdx.x;
    s[threadIdx.x] = (i < NN) ? cnt[i] : 0;
    __syncthreads();
    for (int o = 128; o > 0; o >>= 1) {
        if (threadIdx.x < o) s[threadIdx.x] += s[threadIdx.x + o];
        __syncthreads();
    }
    if (threadIdx.x == 0) csum[blockIdx.x] = s[0];
}

__global__ void k_scan2(const int* __restrict__ csum, int* __restrict__ csum2, int nb) {
    __shared__ int s[512];
    int t = threadIdx.x;
    int v = (t < nb) ? csum[t] : 0;
    s[t] = v; __syncthreads();
    for (int o = 1; o < 512; o <<= 1) {
        int x = (t >= o) ? s[t - o] : 0;
        __syncthreads();
        s[t] += x;
        __syncthreads();
    }
    if (t < nb) csum2[t] = s[t] - v;  // exclusive
}

// indptr + dinv in one pass
__global__ void k_scan3d(const int* __restrict__ cnt, const int* __restrict__ csum2,
                         int* __restrict__ indptr, float* __restrict__ dinv) {
    __shared__ int s[256];
    int t = threadIdx.x;
    int i = blockIdx.x * 256 + t;
    int v = (i < NN) ? cnt[i] : 0;
    s[t] = v; __syncthreads();
    for (int o = 1; o < 256; o <<= 1) {
        int x = (t >= o) ? s[t - o] : 0;
        __syncthreads();
        s[t] += x;
        __syncthreads();
    }
    if (i < NN) {
        indptr[i] = csum2[blockIdx.x] + s[t] - v;
        dinv[i] = 1.0f / sqrtf((float)v + 2.0f);
    }
    if (i == 0) indptr[NN] = NE;
}

__global__ void k_scatter(const int* __restrict__ row, const int* __restrict__ col,
                          const int* __restrict__ indptr,
                          int* __restrict__ fill, int* __restrict__ esrc) {
    int e = blockIdx.x * 256 + threadIdx.x;
    if (e >= NE) return;
    int r = row[e], c = col[e];
    int pos = indptr[c] + atomicAdd(&fill[c], 1);
    esrc[pos] = r;
}

// batch is sorted: graph starts via boundary detection
__global__ void k_gbounds(const int* __restrict__ batch, int* __restrict__ gstart) {
    int i = blockIdx.x * 256 + threadIdx.x;
    if (i >= NN) return;
    int b = batch[i];
    int pb = (i == 0) ? -1 : batch[i - 1];
    for (int g = pb + 1; g <= b; g++) gstart[g] = i;
    if (i == NN - 1) {
        for (int g = b + 1; g <= NG; g++) gstart[g] = NN;
    }
}

// ----- weight conversion: split-fp16, Wt[n][k] layout, lo scaled by 2048 -----
__global__ void k_convW(const float* __restrict__ W1, __half* __restrict__ w1h, __half* __restrict__ w1l,
                        const float* __restrict__ W2, __half* __restrict__ w2h, __half* __restrict__ w2l,
                        const float* __restrict__ W3, __half* __restrict__ w3h, __half* __restrict__ w3l,
                        const float* __restrict__ W4, __half* __restrict__ w4h, __half* __restrict__ w4l,
                        const float* __restrict__ W5, __half* __restrict__ w5h, __half* __restrict__ w5l) {
    int b = blockIdx.x, t = threadIdx.x;
    const float* W; __half *Wh, *Wl; int K, KCP, idx;
    if (b < 168) {            // layer 1: 112*384 = 43008 = 168 blocks
        W = W1; Wh = w1h; Wl = w1l; K = 336; KCP = 384; idx = b * 256 + t;
    } else {                  // layers 2..5: 112*128 = 14336 = 56 blocks each
        int li = (b - 168) / 56;
        int lb = (b - 168) % 56;
        const float* Ws[4] = {W2, W3, W4, W5};
        __half* Whs[4] = {w2h, w3h, w4h, w5h};
        __half* Wls[4] = {w2l, w3l, w4l, w5l};
        W = Ws[li]; Wh = Whs[li]; Wl = Wls[li]; K = 100; KCP = 128; idx = lb * 256 + t;
    }
    int n = idx / KCP, k = idx - n * KCP;
    float v = (n < 100 && k < K) ? W[k * 100 + n] : 0.f;
    __half hi = __float2half(v);
    Wh[idx] = hi;
    // residual scaled by 2^11 -> stays in fp16 normal range (no denorm loss)
    Wl[idx] = __float2half((v - __half2float(hi)) * 2048.f);
}

__device__ __forceinline__ f16x8 cvt8(float4 v0, float4 v1) {
    __half2 p0 = __floats2half2_rn(v0.x, v0.y);
    __half2 p1 = __floats2half2_rn(v0.z, v0.w);
    __half2 p2 = __floats2half2_rn(v1.x, v1.y);
    __half2 p3 = __floats2half2_rn(v1.z, v1.w);
    union { uint4 u; f16x8 f; } c;
    c.u.x = __builtin_bit_cast(unsigned, p0);
    c.u.y = __builtin_bit_cast(unsigned, p1);
    c.u.z = __builtin_bit_cast(unsigned, p2);
    c.u.w = __builtin_bit_cast(unsigned, p3);
    return c.f;
}

__device__ __forceinline__ f16x8 load_cvt(const float* __restrict__ x, int row, int k) {
    float4 v0 = make_float4(0.f, 0.f, 0.f, 0.f), v1 = v0;
    if (row < NN && k < 336) {
        const float* p = x + (size_t)row * 336 + k;
        v0 = *(const float4*)p;
        v1 = *(const float4*)(p + 4);
    }
    return cvt8(v0, v1);
}

// ---- layer-1 GEMM: fp32 x (direct-global, cvt to fp16) x split-fp16 W ----
// No LDS, no barriers. 128 rows/block, 32 rows/wave (2 row-groups share B frags).
__global__ __launch_bounds__(256, 3) void k_gemmX(const float* __restrict__ x,
                                                  const __half* __restrict__ Whi,
                                                  const __half* __restrict__ Wlo,
                                                  const float* __restrict__ dinv,
                                                  __half* __restrict__ out) {
    int t = threadIdx.x;
    int lane = t & 63, wv = t >> 6;
    int l15 = lane & 15, quad = lane >> 4;
    int rowbase = blockIdx.x * 128 + wv * 32;

    f32x4 acch[2][7], accl[2][7];
#pragma unroll
    for (int rg = 0; rg < 2; rg++)
#pragma unroll
        for (int i = 0; i < 7; i++)
#pragma unroll
            for (int r = 0; r < 4; r++) { acch[rg][i][r] = 0.f; accl[rg][i][r] = 0.f; }

    int ar0 = rowbase + l15;
    const __half* bh0 = Whi + (size_t)l15 * 384 + quad * 8;
    const __half* bl0 = Wlo + (size_t)l15 * 384 + quad * 8;

#pragma unroll
    for (int ks = 0; ks < 11; ks++) {           // K=336 live (tail zero-guarded)
        int k = ks * 32 + quad * 8;
        f16x8 a0 = load_cvt(x, ar0, k);
        f16x8 a1 = load_cvt(x, ar0 + 16, k);
#pragma unroll
        for (int tt = 0; tt < 7; tt++) {
            f16x8 bh = *(const f16x8*)(bh0 + (size_t)tt * 16 * 384 + ks * 32);
            f16x8 bl = *(const f16x8*)(bl0 + (size_t)tt * 16 * 384 + ks * 32);
            acch[0][tt] = __builtin_amdgcn_mfma_f32_16x16x32_f16(a0, bh, acch[0][tt], 0, 0, 0);
            accl[0][tt] = __builtin_amdgcn_mfma_f32_16x16x32_f16(a0, bl, accl[0][tt], 0, 0, 0);
            acch[1][tt] = __builtin_amdgcn_mfma_f32_16x16x32_f16(a1, bh, acch[1][tt], 0, 0, 0);
            accl[1][tt] = __builtin_amdgcn_mfma_f32_16x16x32_f16(a1, bl, accl[1][tt], 0, 0, 0);
        }
    }

#pragma unroll
    for (int rg = 0; rg < 2; rg++) {
        int gr0 = rowbase + rg * 16 + quad * 4;
        float dv[4];
#pragma unroll
        for (int reg = 0; reg < 4; reg++) dv[reg] = (gr0 + reg < NN) ? dinv[gr0 + reg] : 0.f;
#pragma unroll
        for (int tt = 0; tt < 7; tt++) {
            int n = tt * 16 + l15;
#pragma unroll
            for (int reg = 0; reg < 4; reg++) {
                int gr = gr0 + reg;
                if (gr < NN)
                    out[(size_t)gr * LDX + n] =
                        __float2half(dv[reg] * (acch[rg][tt][reg] + accl[rg][tt][reg] * (1.f / 2048.f)));
            }
        }
        if (l15 < 8) {  // zero k-pad cols 112..127 so next layer's A-frags are clean
#pragma unroll
            for (int reg = 0; reg < 4; reg++) {
                int gr = gr0 + reg;
                if (gr < NN) *(unsigned int*)(out + (size_t)gr * LDX + 112 + l15 * 2) = 0u;
            }
        }
    }
}

// ---- layers 2-5 GEMM: fp16 act table x split-fp16 W, fully direct-global ----
__global__ __launch_bounds__(256, 3) void k_gemmH(const __half* __restrict__ act,
                                                  const __half* __restrict__ Whi,
                                                  const __half* __restrict__ Wlo,
                                                  const float* __restrict__ dinv,
                                                  __half* __restrict__ out) {
    int t = threadIdx.x;
    int lane = t & 63, wv = t >> 6;
    int l15 = lane & 15, quad = lane >> 4;
    int rowbase = blockIdx.x * 128 + wv * 32;

    f32x4 acch[2][7], accl[2][7];
#pragma unroll
    for (int rg = 0; rg < 2; rg++)
#pragma unroll
        for (int i = 0; i < 7; i++)
#pragma unroll
            for (int r = 0; r < 4; r++) { acch[rg][i][r] = 0.f; accl[rg][i][r] = 0.f; }

    // Rows >= NN: clamp to row NN-1 (valid memory; results discarded in epilogue).
    int r0 = min(rowbase + l15, NN - 1);
    int r1 = min(rowbase + l15 + 16, NN - 1);
    const __half* a0p = act + (size_t)r0 * LDX + quad * 8;
    const __half* a1p = act + (size_t)r1 * LDX + quad * 8;
    const __half* bh0 = Whi + (size_t)l15 * 128 + quad * 8;
    const __half* bl0 = Wlo + (size_t)l15 * 128 + quad * 8;

#pragma unroll
    for (int ks = 0; ks < 4; ks++) {
        f16x8 a0 = *(const f16x8*)(a0p + ks * 32);
        f16x8 a1 = *(const f16x8*)(a1p + ks * 32);
#pragma unroll
        for (int tt = 0; tt < 7; tt++) {
            f16x8 bh = *(const f16x8*)(bh0 + (size_t)tt * 16 * 128 + ks * 32);
            f16x8 bl = *(const f16x8*)(bl0 + (size_t)tt * 16 * 128 + ks * 32);
            acch[0][tt] = __builtin_amdgcn_mfma_f32_16x16x32_f16(a0, bh, acch[0][tt], 0, 0, 0);
            accl[0][tt] = __builtin_amdgcn_mfma_f32_16x16x32_f16(a0, bl, accl[0][tt], 0, 0, 0);
            acch[1][tt] = __builtin_amdgcn_mfma_f32_16x16x32_f16(a1, bh, acch[1][tt], 0, 0, 0);
            accl[1][tt] = __builtin_amdgcn_mfma_f32_16x16x32_f16(a1, bl, accl[1][tt], 0, 0, 0);
        }
    }

#pragma unroll
    for (int rg = 0; rg < 2; rg++) {
        int gr0 = rowbase + rg * 16 + quad * 4;
        float dv[4];
#pragma unroll
        for (int reg = 0; reg < 4; reg++) dv[reg] = (gr0 + reg < NN) ? dinv[gr0 + reg] : 0.f;
#pragma unroll
        for (int tt = 0; tt < 7; tt++) {
            int n = tt * 16 + l15;
#pragma unroll
            for (int reg = 0; reg < 4; reg++) {
                int gr = gr0 + reg;
                if (gr < NN)
                    out[(size_t)gr * LDX + n] =
                        __float2half(dv[reg] * (acch[rg][tt][reg] + accl[rg][tt][reg] * (1.f / 2048.f)));
            }
        }
        if (l15 < 8) {
#pragma unroll
            for (int reg = 0; reg < 4; reg++) {
                int gr = gr0 + reg;
                if (gr < NN) *(unsigned int*)(out + (size_t)gr * LDX + 112 + l15 * 2) = 0u;
            }
        }
    }
}

// ---- aggregation core: gathers fp16 rows (4 cache lines/row), fp32 accumulate ----
__device__ __forceinline__ void agg_core(const __half* __restrict__ xs,
                                         const int* __restrict__ esrc,
                                         int beg, int end, int lane, int col,
                                         float& ax, float& ay) {
    ax = 0.f; ay = 0.f;
    for (int c = beg; c < end; c += 64) {
        int m = min(64, end - c);
        int se = 0;
        if (lane < m) se = esrc[c + lane];
        int j = 0;
        for (; j + 16 <= m; j += 16) {
            __half2 v[16];
#pragma unroll
            for (int u = 0; u < 16; u++) {
                int s = __builtin_amdgcn_readlane(se, j + u);
                v[u] = *(const __half2*)(xs + (size_t)s * LDX + col);
            }
#pragma unroll
            for (int u = 0; u < 16; u++) {
                float2 f = __half22float2(v[u]);
                ax += f.x; ay += f.y;
            }
        }
        for (; j + 8 <= m; j += 8) {
            __half2 v[8];
#pragma unroll
            for (int u = 0; u < 8; u++) {
                int s = __builtin_amdgcn_readlane(se, j + u);
                v[u] = *(const __half2*)(xs + (size_t)s * LDX + col);
            }
#pragma unroll
            for (int u = 0; u < 8; u++) {
                float2 f = __half22float2(v[u]);
                ax += f.x; ay += f.y;
            }
        }
        for (; j + 4 <= m; j += 4) {
            __half2 v[4];
#pragma unroll
            for (int u = 0; u < 4; u++) {
                int s = __builtin_amdgcn_readlane(se, j + u);
                v[u] = *(const __half2*)(xs + (size_t)s * LDX + col);
            }
#pragma unroll
            for (int u = 0; u < 4; u++) {
                float2 f = __half22float2(v[u]);
                ax += f.x; ay += f.y;
            }
        }
        for (; j < m; j++) {
            int s = __builtin_amdgcn_readlane(se, j);
            float2 f = __half22float2(*(const __half2*)(xs + (size_t)s * LDX + col));
            ax += f.x; ay += f.y;
        }
    }
}

// ---- agg, layers 1-4: writes single fp16 activation table (128-stride, padded) ----
__global__ __launch_bounds__(256) void k_aggS(const __half* __restrict__ xs,
                                              const int* __restrict__ indptr,
                                              const int* __restrict__ esrc,
                                              const float* __restrict__ dinv,
                                              const float* __restrict__ bias,
                                              __half* __restrict__ hh) {
    int wave = threadIdx.x >> 6;
    int lane = threadIdx.x & 63;
    int n = blockIdx.x * 4 + wave;
    if (n >= NN) return;
    int beg = indptr[n], end = indptr[n + 1];
    int col = (lane < 50) ? lane * 2 : 0;
    float ax, ay;
    agg_core(xs, esrc, beg, end, lane, col, ax, ay);
    if (lane < 50) {
        float di = dinv[n];
        float2 xv = __half22float2(*(const __half2*)(xs + (size_t)n * LDX + col));
        float2 bv = *(const float2*)(bias + lane * 2);
        float hx = fmaxf(di * (ax + 2.f * xv.x) + bv.x, 0.f);
        float hy = fmaxf(di * (ay + 2.f * xv.y) + bv.y, 0.f);
        *(__half2*)(hh + (size_t)n * LDX + col) = __floats2half2_rn(hx, hy);
    } else {
        int pc = 100 + (lane - 50) * 2;  // zero pad cols 100..127
        *(unsigned int*)(hh + (size_t)n * LDX + pc) = 0u;
    }
}

// ---- agg, layer 5: fp32 epilogue for pooling ----
__global__ __launch_bounds__(256) void k_agg(const __half* __restrict__ xs,
                                             const int* __restrict__ indptr,
                                             const int* __restrict__ esrc,
                                             const float* __restrict__ dinv,
                                             const float* __restrict__ bias,
                                             float* __restrict__ hout) {
    int wave = threadIdx.x >> 6;
    int lane = threadIdx.x & 63;
    int n = blockIdx.x * 4 + wave;
    if (n >= NN) return;
    int beg = indptr[n], end = indptr[n + 1];
    int col = (lane < 50) ? lane * 2 : 0;
    float ax, ay;
    agg_core(xs, esrc, beg, end, lane, col, ax, ay);
    if (lane < 50) {
        float di = dinv[n];
        float2 xv = __half22float2(*(const __half2*)(xs + (size_t)n * LDX + col));
        float2 bv = *(const float2*)(bias + lane * 2);
        float2 r;
        r.x = fmaxf(di * (ax + 2.f * xv.x) + bv.x, 0.f);
        r.y = fmaxf(di * (ay + 2.f * xv.y) + bv.y, 0.f);
        *(float2*)(hout + (size_t)n * LDA + col) = r;
    }
}

// ---------------- pooling (8-way ILP over nodes) ----------------
__global__ __launch_bounds__(128) void k_pool(const float* __restrict__ h,
                                              const int* __restrict__ gstart,
                                              float* __restrict__ pooled) {
    int g = blockIdx.x, t = threadIdx.x;
    if (t >= 100) return;
    int st = gstart[g];
    int cnt = gstart[g + 1] - st;
    float s0 = 0.f, s1 = 0.f, s2 = 0.f, s3 = 0.f;
    float s4 = 0.f, s5 = 0.f, s6 = 0.f, s7 = 0.f;
    int i = 0;
    for (; i + 8 <= cnt; i += 8) {
        s0 += h[(size_t)(st + i) * LDA + t];
        s1 += h[(size_t)(st + i + 1) * LDA + t];
        s2 += h[(size_t)(st + i + 2) * LDA + t];
        s3 += h[(size_t)(st + i + 3) * LDA + t];
        s4 += h[(size_t)(st + i + 4) * LDA + t];
        s5 += h[(size_t)(st + i + 5) * LDA + t];
        s6 += h[(size_t)(st + i + 6) * LDA + t];
        s7 += h[(size_t)(st + i + 7) * LDA + t];
    }
    for (; i < cnt; i++) s0 += h[(size_t)(st + i) * LDA + t];
    float s = ((s0 + s1) + (s2 + s3)) + ((s4 + s5) + (s6 + s7));
    pooled[g * 100 + t] = s / (float)(cnt > 0 ? cnt : 1);
}

// ---------------- MLP head ----------------
__global__ void k_mlp(const float* __restrict__ pooled,
                      const float* __restrict__ Wl1, const float* __restrict__ bl1,
                      const float* __restrict__ Wl2, const float* __restrict__ bl2,
                      const float* __restrict__ Wl3, const float* __restrict__ bl3,
                      float* __restrict__ out) {
    __shared__ float p[100], q[100];
    int g = blockIdx.x, t = threadIdx.x;
    if (t < 100) p[t] = pooled[g * 100 + t];
    __syncthreads();
    float s1 = 0.f;
    if (t < 100) {
        s1 = bl1[t];
        for (int k = 0; k < 100; k++) s1 += p[k] * Wl1[k * 100 + t];
        s1 = fmaxf(s1, 0.f);
    }
    __syncthreads();
    if (t < 100) q[t] = s1;
    __syncthreads();
    float s2 = 0.f;
    if (t < 100) {
        s2 = bl2[t];
        for (int k = 0; k < 100; k++) s2 += q[k] * Wl2[k * 100 + t];
        s2 = fmaxf(s2, 0.f);
    }
    __syncthreads();
    if (t < 100) p[t] = s2;
    __syncthreads();
    if (t < 29) {
        float s3 = bl3[t];
        for (int k = 0; k < 100; k++) s3 += p[k] * Wl3[k * 29 + t];
        out[g * 29 + t] = s3;
    }
}

// ---------------- launch ----------------
extern "C" void kernel_launch(void* const* d_in, const int* in_sizes, int n_in,
                              void* d_out, int out_size, void* d_ws, size_t ws_size,
                              hipStream_t stream) {
    const float* x     = (const float*)d_in[0];
    const int*   ei    = (const int*)d_in[1];
    const int*   batch = (const int*)d_in[2];
    const float* W1 = (const float*)d_in[3];  const float* b1 = (const float*)d_in[4];
    const float* W2 = (const float*)d_in[5];  const float* b2 = (const float*)d_in[6];
    const float* W3 = (const float*)d_in[7];  const float* b3 = (const float*)d_in[8];
    const float* W4 = (const float*)d_in[9];  const float* b4 = (const float*)d_in[10];
    const float* W5 = (const float*)d_in[11]; const float* b5 = (const float*)d_in[12];
    const float* Wl1 = (const float*)d_in[13]; const float* bl1 = (const float*)d_in[14];
    const float* Wl2 = (const float*)d_in[15]; const float* bl2 = (const float*)d_in[16];
    const float* Wl3 = (const float*)d_in[17]; const float* bl3 = (const float*)d_in[18];
    float* out = (float*)d_out;

    const int* row = ei;
    const int* col = ei + NE;

    uintptr_t base = (uintptr_t)d_ws;
    auto alloc = [&](size_t bytes) -> void* {
        void* p = (void*)base;
        base += (bytes + 255) & ~(size_t)255;
        return p;
    };
    int*   cnts   = (int*)alloc((size_t)(2 * NN) * 4);
    int*   degcnt = cnts;
    int*   fill   = cnts + NN;
    float* dinv   = (float*)alloc(NN * 4);
    int*   indptr = (int*)alloc((NN + 1) * 4);
    int*   csum   = (int*)alloc(512 * 4);
    int*   csum2  = (int*)alloc(512 * 4);
    int*   gstart = (int*)alloc((NG + 1) * 4);
    int*   esrc   = (int*)alloc((size_t)NE * 4);
    __half* xsh   = (__half*)alloc((size_t)NN * LDX * 2);
    __half* hh    = (__half*)alloc((size_t)NN * LDX * 2);
    float* h      = (float*)alloc((size_t)NN * LDA * 4);
    float* pooled = (float*)alloc((size_t)NG * 100 * 4);
    __half* w1hi = (__half*)alloc((size_t)112 * 384 * 2);
    __half* w1lo = (__half*)alloc((size_t)112 * 384 * 2);
    __half* w2hi = (__half*)alloc((size_t)112 * 128 * 2);
    __half* w2lo = (__half*)alloc((size_t)112 * 128 * 2);
    __half* w3hi = (__half*)alloc((size_t)112 * 128 * 2);
    __half* w3lo = (__half*)alloc((size_t)112 * 128 * 2);
    __half* w4hi = (__half*)alloc((size_t)112 * 128 * 2);
    __half* w4lo = (__half*)alloc((size_t)112 * 128 * 2);
    __half* w5hi = (__half*)alloc((size_t)112 * 128 * 2);
    __half* w5lo = (__half*)alloc((size_t)112 * 128 * 2);

    hipMemsetAsync(cnts, 0, (size_t)(2 * NN) * 4, stream);

    const int NB = (NN + 255) / 256;  // 391
    k_deg<<<(NE + 255) / 256, 256, 0, stream>>>(col, degcnt);
    k_scan1<<<NB, 256, 0, stream>>>(degcnt, csum);
    k_scan2<<<1, 512, 0, stream>>>(csum, csum2, NB);
    k_scan3d<<<NB, 256, 0, stream>>>(degcnt, csum2, indptr, dinv);
    k_scatter<<<(NE + 255) / 256, 256, 0, stream>>>(row, col, indptr, fill, esrc);
    k_gbounds<<<NB, 256, 0, stream>>>(batch, gstart);
    k_convW<<<392, 256, 0, stream>>>(W1, w1hi, w1lo, W2, w2hi, w2lo,
                                     W3, w3hi, w3lo, W4, w4hi, w4lo,
                                     W5, w5hi, w5lo);

    const int GEMM_GRID = (NN + 127) / 128;  // 782
    const int AGG_GRID = (NN + 3) / 4;       // 25000

    k_gemmX<<<GEMM_GRID, 256, 0, stream>>>(x, w1hi, w1lo, dinv, xsh);
    k_aggS<<<AGG_GRID, 256, 0, stream>>>(xsh, indptr, esrc, dinv, b1, hh);
    k_gemmH<<<GEMM_GRID, 256, 0, stream>>>(hh, w2hi, w2lo, dinv, xsh);
    k_aggS<<<AGG_GRID, 256, 0, stream>>>(xsh, indptr, esrc, dinv, b2, hh);
    k_gemmH<<<GEMM_GRID, 256, 0, stream>>>(hh, w3hi, w3lo, dinv, xsh);
    k_aggS<<<AGG_GRID, 256, 0, stream>>>(xsh, indptr, esrc, dinv, b3, hh);
    k_gemmH<<<GEMM_GRID, 256, 0, stream>>>(hh, w4hi, w4lo, dinv, xsh);
    k_aggS<<<AGG_GRID, 256, 0, stream>>>(xsh, indptr, esrc, dinv, b4, hh);
    k_gemmH<<<GEMM_GRID, 256, 0, stream>>>(hh, w5hi, w5lo, dinv, xsh);
    k_agg<<<AGG_GRID, 256, 0, stream>>>(xsh, indptr, esrc, dinv, b5, h);

    k_pool<<<NG, 128, 0, stream>>>(h, gstart, pooled);
    k_mlp<<<NG, 128, 0, stream>>>(pooled, Wl1, bl1, Wl2, bl2, Wl3, bl3, out);
}

// Round 4
// 846.208 us; speedup vs baseline: 1.2151x; 1.2151x over previous
//
#include <hip/hip_runtime.h>
#include <hip/hip_fp16.h>
#include <stdint.h>

#define NN 100000
#define NE 1600000
#define NG 1000
#define LDA 112   // fp32 row stride for h (pooling input): 448 B
#define LDX 128   // half row stride for fp16 activation tables: 256 B

typedef float f32x4 __attribute__((ext_vector_type(4)));
typedef _Float16 f16x8 __attribute__((ext_vector_type(8)));

// async global->LDS, 16 B per lane (LDS dest = wave-uniform base + lane*16)
__device__ __forceinline__ void load_lds16(const void* g, void* l) {
    __builtin_amdgcn_global_load_lds((const __attribute__((address_space(1))) unsigned int*)g,
                                     (__attribute__((address_space(3))) unsigned int*)l,
                                     16, 0, 0);
}

// ---------------- degree ----------------
__global__ void k_deg(const int* __restrict__ col, int* __restrict__ degcnt) {
    int e = blockIdx.x * 256 + threadIdx.x;
    if (e < NE) atomicAdd(&degcnt[col[e]], 1);
}

// ---------------- prefix scans for CSR ----------------
__global__ void k_scan1(const int* __restrict__ cnt, int* __restrict__ csum) {
    __shared__ int s[256];
    int i = blockIdx.x * 256 + threadIdx.x;
    s[threadIdx.x] = (i < NN) ? cnt[i] : 0;
    __syncthreads();
    for (int o = 128; o > 0; o >>= 1) {
        if (threadIdx.x < o) s[threadIdx.x] += s[threadIdx.x + o];
        __syncthreads();
    }
    if (threadIdx.x == 0) csum[blockIdx.x] = s[0];
}

__global__ void k_scan2(const int* __restrict__ csum, int* __restrict__ csum2, int nb) {
    __shared__ int s[512];
    int t = threadIdx.x;
    int v = (t < nb) ? csum[t] : 0;
    s[t] = v; __syncthreads();
    for (int o = 1; o < 512; o <<= 1) {
        int x = (t >= o) ? s[t - o] : 0;
        __syncthreads();
        s[t] += x;
        __syncthreads();
    }
    if (t < nb) csum2[t] = s[t] - v;  // exclusive
}

// indptr + dinv in one pass
__global__ void k_scan3d(const int* __restrict__ cnt, const int* __restrict__ csum2,
                         int* __restrict__ indptr, float* __restrict__ dinv) {
    __shared__ int s[256];
    int t = threadIdx.x;
    int i = blockIdx.x * 256 + t;
    int v = (i < NN) ? cnt[i] : 0;
    s[t] = v; __syncthreads();
    for (int o = 1; o < 256; o <<= 1) {
        int x = (t >= o) ? s[t - o] : 0;
        __syncthreads();
        s[t] += x;
        __syncthreads();
    }
    if (i < NN) {
        indptr[i] = csum2[blockIdx.x] + s[t] - v;
        dinv[i] = 1.0f / sqrtf((float)v + 2.0f);
    }
    if (i == 0) indptr[NN] = NE;
}

__global__ void k_scatter(const int* __restrict__ row, const int* __restrict__ col,
                          const int* __restrict__ indptr,
                          int* __restrict__ fill, int* __restrict__ esrc) {
    int e = blockIdx.x * 256 + threadIdx.x;
    if (e >= NE) return;
    int r = row[e], c = col[e];
    int pos = indptr[c] + atomicAdd(&fill[c], 1);
    esrc[pos] = r;
}

// batch is sorted: graph starts via boundary detection
__global__ void k_gbounds(const int* __restrict__ batch, int* __restrict__ gstart) {
    int i = blockIdx.x * 256 + threadIdx.x;
    if (i >= NN) return;
    int b = batch[i];
    int pb = (i == 0) ? -1 : batch[i - 1];
    for (int g = pb + 1; g <= b; g++) gstart[g] = i;
    if (i == NN - 1) {
        for (int g = b + 1; g <= NG; g++) gstart[g] = NN;
    }
}

// ----- weight conversion: split-fp16, Wt[n][k], lo scaled by 2048 -----
// Stored PRE-SWIZZLED: within each 128-half row-chunk, half-col k -> k ^ ((n&7)<<3)
// (byte-swizzle ((n&7)<<4)). LDS staging is then a linear copy; LDS reads use the
// same XOR -> conflict-free ds_read_b128.
__global__ void k_convW(const float* __restrict__ W1, __half* __restrict__ w1h, __half* __restrict__ w1l,
                        const float* __restrict__ W2, __half* __restrict__ w2h, __half* __restrict__ w2l,
                        const float* __restrict__ W3, __half* __restrict__ w3h, __half* __restrict__ w3l,
                        const float* __restrict__ W4, __half* __restrict__ w4h, __half* __restrict__ w4l,
                        const float* __restrict__ W5, __half* __restrict__ w5h, __half* __restrict__ w5l) {
    int b = blockIdx.x, t = threadIdx.x;
    const float* W; __half *Wh, *Wl; int K, KCP, idx;
    if (b < 168) {            // layer 1: 112*384 = 43008 = 168 blocks
        W = W1; Wh = w1h; Wl = w1l; K = 336; KCP = 384; idx = b * 256 + t;
    } else {                  // layers 2..5: 112*128 = 14336 = 56 blocks each
        int li = (b - 168) / 56;
        int lb = (b - 168) % 56;
        const float* Ws[4] = {W2, W3, W4, W5};
        __half* Whs[4] = {w2h, w3h, w4h, w5h};
        __half* Wls[4] = {w2l, w3l, w4l, w5l};
        W = Ws[li]; Wh = Whs[li]; Wl = Wls[li]; K = 100; KCP = 128; idx = lb * 256 + t;
    }
    int n = idx / KCP, k = idx - n * KCP;
    float v = (n < 100 && k < K) ? W[k * 100 + n] : 0.f;
    __half hi = __float2half(v);
    __half lo = __float2half((v - __half2float(hi)) * 2048.f);
    int kc = k & 127;
    size_t so = (size_t)n * KCP + (k - kc) + (kc ^ ((n & 7) << 3));
    Wh[so] = hi;
    Wl[so] = lo;
}

__device__ __forceinline__ f16x8 cvt8(float4 v0, float4 v1) {
    __half2 p0 = __floats2half2_rn(v0.x, v0.y);
    __half2 p1 = __floats2half2_rn(v0.z, v0.w);
    __half2 p2 = __floats2half2_rn(v1.x, v1.y);
    __half2 p3 = __floats2half2_rn(v1.z, v1.w);
    union { uint4 u; f16x8 f; } c;
    c.u.x = __builtin_bit_cast(unsigned, p0);
    c.u.y = __builtin_bit_cast(unsigned, p1);
    c.u.z = __builtin_bit_cast(unsigned, p2);
    c.u.w = __builtin_bit_cast(unsigned, p3);
    return c.f;
}

// ---- layer-1 GEMM: 512 thr / 8 waves / 128 rows; W chunk staged in LDS ----
__global__ __launch_bounds__(512, 4) void k_gemmX(const float* __restrict__ x,
                                                  const __half* __restrict__ Whi,
                                                  const __half* __restrict__ Wlo,
                                                  const float* __restrict__ dinv,
                                                  __half* __restrict__ out) {
    __shared__ __align__(16) __half Hs[112 * 128];
    __shared__ __align__(16) __half Ls[112 * 128];
    int t = threadIdx.x;
    int lane = t & 63, wv = t >> 6;
    int l15 = lane & 15, quad = lane >> 4;
    int rowbase = blockIdx.x * 128;
    int arow = rowbase + wv * 16 + l15;

    f32x4 acch[7], accl[7];
#pragma unroll
    for (int i = 0; i < 7; i++)
#pragma unroll
        for (int r = 0; r < 4; r++) { acch[i][r] = 0.f; accl[i][r] = 0.f; }

    int swz = (l15 & 7) << 4;

    for (int k0 = 0; k0 < 384; k0 += 128) {
        if (k0) __syncthreads();
        // A frags for this chunk: fp32 -> fp16 (each element read once)
        f16x8 a[4];
#pragma unroll
        for (int ks = 0; ks < 4; ks++) {
            int k = k0 + ks * 32 + quad * 8;
            float4 v0 = make_float4(0.f, 0.f, 0.f, 0.f), v1 = v0;
            if (arow < NN && k < 336) {
                const float* p = x + (size_t)arow * 336 + k;
                v0 = *(const float4*)p;
                v1 = *(const float4*)(p + 4);
            }
            a[ks] = cvt8(v0, v1);
        }
        // stage W chunk [112][128] hi+lo: 56 wave-chunks of 1 KB (wave-uniform table pick)
#pragma unroll
        for (int cch = 0; cch < 7; cch++) {
            int g = wv + cch * 8;          // 0..55, uniform per wave
            int tb = (g >= 28);
            int o = (g - (tb ? 28 : 0)) * 1024 + lane * 16;
            int r = o >> 8, cc = o & 255;
            size_t src = (size_t)r * 768 + (size_t)(k0 * 2) + cc;
            if (!tb) load_lds16((const char*)Whi + src, (char*)Hs + o);
            else     load_lds16((const char*)Wlo + src, (char*)Ls + o);
        }
        __syncthreads();
#pragma unroll
        for (int ks = 0; ks < 4; ks++) {
            int cb = (ks * 64 + quad * 16) ^ swz;
#pragma unroll
            for (int tt = 0; tt < 7; tt++) {
                int ro = (tt * 16 + l15) * 256;
                f16x8 bh = *(const f16x8*)((const char*)Hs + ro + cb);
                f16x8 bl = *(const f16x8*)((const char*)Ls + ro + cb);
                acch[tt] = __builtin_amdgcn_mfma_f32_16x16x32_f16(a[ks], bh, acch[tt], 0, 0, 0);
                accl[tt] = __builtin_amdgcn_mfma_f32_16x16x32_f16(a[ks], bl, accl[tt], 0, 0, 0);
            }
        }
    }

    int gr0 = rowbase + wv * 16 + quad * 4;
    float dv[4];
#pragma unroll
    for (int reg = 0; reg < 4; reg++) dv[reg] = (gr0 + reg < NN) ? dinv[gr0 + reg] : 0.f;
#pragma unroll
    for (int tt = 0; tt < 7; tt++) {
        int n = tt * 16 + l15;
#pragma unroll
        for (int reg = 0; reg < 4; reg++) {
            int gr = gr0 + reg;
            if (gr < NN)
                out[(size_t)gr * LDX + n] =
                    __float2half(dv[reg] * (acch[tt][reg] + accl[tt][reg] * (1.f / 2048.f)));
        }
    }
    if (l15 < 8) {  // zero k-pad cols 112..127 so next layer's A-frags are clean
#pragma unroll
        for (int reg = 0; reg < 4; reg++) {
            int gr = gr0 + reg;
            if (gr < NN) *(unsigned int*)(out + (size_t)gr * LDX + 112 + l15 * 2) = 0u;
        }
    }
}

// ---- layers 2-5 GEMM: 512 thr / 8 waves / 128 rows; full W in LDS, 1 barrier ----
__global__ __launch_bounds__(512, 4) void k_gemmH(const __half* __restrict__ act,
                                                  const __half* __restrict__ Whi,
                                                  const __half* __restrict__ Wlo,
                                                  const float* __restrict__ dinv,
                                                  __half* __restrict__ out) {
    __shared__ __align__(16) __half Hs[112 * 128];
    __shared__ __align__(16) __half Ls[112 * 128];
    int t = threadIdx.x;
    int lane = t & 63, wv = t >> 6;
    int l15 = lane & 15, quad = lane >> 4;
    int rowbase = blockIdx.x * 128;
    int ar = min(rowbase + wv * 16 + l15, NN - 1);  // clamp: results discarded

    // A frags: 4 x 16 B per lane, issued before the W DMA (latency overlaps)
    const char* ap = (const char*)act + (size_t)ar * 256;
    f16x8 a[4];
#pragma unroll
    for (int ks = 0; ks < 4; ks++)
        a[ks] = *(const f16x8*)(ap + ks * 64 + quad * 16);

    // stage full W [112][128] hi+lo (pre-swizzled, linear copy)
#pragma unroll
    for (int cch = 0; cch < 7; cch++) {
        int g = wv + cch * 8;
        int tb = (g >= 28);
        int o = (g - (tb ? 28 : 0)) * 1024 + lane * 16;
        if (!tb) load_lds16((const char*)Whi + o, (char*)Hs + o);
        else     load_lds16((const char*)Wlo + o, (char*)Ls + o);
    }

    f32x4 acch[7], accl[7];
#pragma unroll
    for (int i = 0; i < 7; i++)
#pragma unroll
        for (int r = 0; r < 4; r++) { acch[i][r] = 0.f; accl[i][r] = 0.f; }

    __syncthreads();
    int swz = (l15 & 7) << 4;
#pragma unroll
    for (int ks = 0; ks < 4; ks++) {
        int cb = (ks * 64 + quad * 16) ^ swz;
#pragma unroll
        for (int tt = 0; tt < 7; tt++) {
            int ro = (tt * 16 + l15) * 256;
            f16x8 bh = *(const f16x8*)((const char*)Hs + ro + cb);
            f16x8 bl = *(const f16x8*)((const char*)Ls + ro + cb);
            acch[tt] = __builtin_amdgcn_mfma_f32_16x16x32_f16(a[ks], bh, acch[tt], 0, 0, 0);
            accl[tt] = __builtin_amdgcn_mfma_f32_16x16x32_f16(a[ks], bl, accl[tt], 0, 0, 0);
        }
    }

    int gr0 = rowbase + wv * 16 + quad * 4;
    float dv[4];
#pragma unroll
    for (int reg = 0; reg < 4; reg++) dv[reg] = (gr0 + reg < NN) ? dinv[gr0 + reg] : 0.f;
#pragma unroll
    for (int tt = 0; tt < 7; tt++) {
        int n = tt * 16 + l15;
#pragma unroll
        for (int reg = 0; reg < 4; reg++) {
            int gr = gr0 + reg;
            if (gr < NN)
                out[(size_t)gr * LDX + n] =
                    __float2half(dv[reg] * (acch[tt][reg] + accl[tt][reg] * (1.f / 2048.f)));
        }
    }
    if (l15 < 8) {
#pragma unroll
        for (int reg = 0; reg < 4; reg++) {
            int gr = gr0 + reg;
            if (gr < NN) *(unsigned int*)(out + (size_t)gr * LDX + 112 + l15 * 2) = 0u;
        }
    }
}

// ---- aggregation core: gathers fp16 rows (4 cache lines/row), fp32 accumulate ----
__device__ __forceinline__ void agg_core(const __half* __restrict__ xs,
                                         const int* __restrict__ esrc,
                                         int beg, int end, int lane, int col,
                                         float& ax, float& ay) {
    ax = 0.f; ay = 0.f;
    for (int c = beg; c < end; c += 64) {
        int m = min(64, end - c);
        int se = 0;
        if (lane < m) se = esrc[c + lane];
        int j = 0;
        for (; j + 16 <= m; j += 16) {
            __half2 v[16];
#pragma unroll
            for (int u = 0; u < 16; u++) {
                int s = __builtin_amdgcn_readlane(se, j + u);
                v[u] = *(const __half2*)(xs + (size_t)s * LDX + col);
            }
#pragma unroll
            for (int u = 0; u < 16; u++) {
                float2 f = __half22float2(v[u]);
                ax += f.x; ay += f.y;
            }
        }
        for (; j + 8 <= m; j += 8) {
            __half2 v[8];
#pragma unroll
            for (int u = 0; u < 8; u++) {
                int s = __builtin_amdgcn_readlane(se, j + u);
                v[u] = *(const __half2*)(xs + (size_t)s * LDX + col);
            }
#pragma unroll
            for (int u = 0; u < 8; u++) {
                float2 f = __half22float2(v[u]);
                ax += f.x; ay += f.y;
            }
        }
        for (; j + 4 <= m; j += 4) {
            __half2 v[4];
#pragma unroll
            for (int u = 0; u < 4; u++) {
                int s = __builtin_amdgcn_readlane(se, j + u);
                v[u] = *(const __half2*)(xs + (size_t)s * LDX + col);
            }
#pragma unroll
            for (int u = 0; u < 4; u++) {
                float2 f = __half22float2(v[u]);
                ax += f.x; ay += f.y;
            }
        }
        for (; j < m; j++) {
            int s = __builtin_amdgcn_readlane(se, j);
            float2 f = __half22float2(*(const __half2*)(xs + (size_t)s * LDX + col));
            ax += f.x; ay += f.y;
        }
    }
}

// ---- agg, layers 1-4: writes single fp16 activation table (128-stride, padded) ----
__global__ __launch_bounds__(256) void k_aggS(const __half* __restrict__ xs,
                                              const int* __restrict__ indptr,
                                              const int* __restrict__ esrc,
                                              const float* __restrict__ dinv,
                                              const float* __restrict__ bias,
                                              __half* __restrict__ hh) {
    int wave = threadIdx.x >> 6;
    int lane = threadIdx.x & 63;
    int n = blockIdx.x * 4 + wave;
    if (n >= NN) return;
    int beg = indptr[n], end = indptr[n + 1];
    int col = (lane < 50) ? lane * 2 : 0;
    float ax, ay;
    agg_core(xs, esrc, beg, end, lane, col, ax, ay);
    if (lane < 50) {
        float di = dinv[n];
        float2 xv = __half22float2(*(const __half2*)(xs + (size_t)n * LDX + col));
        float2 bv = *(const float2*)(bias + lane * 2);
        float hx = fmaxf(di * (ax + 2.f * xv.x) + bv.x, 0.f);
        float hy = fmaxf(di * (ay + 2.f * xv.y) + bv.y, 0.f);
        *(__half2*)(hh + (size_t)n * LDX + col) = __floats2half2_rn(hx, hy);
    } else {
        int pc = 100 + (lane - 50) * 2;  // zero pad cols 100..127
        *(unsigned int*)(hh + (size_t)n * LDX + pc) = 0u;
    }
}

// ---- agg, layer 5: fp32 epilogue for pooling ----
__global__ __launch_bounds__(256) void k_agg(const __half* __restrict__ xs,
                                             const int* __restrict__ indptr,
                                             const int* __restrict__ esrc,
                                             const float* __restrict__ dinv,
                                             const float* __restrict__ bias,
                                             float* __restrict__ hout) {
    int wave = threadIdx.x >> 6;
    int lane = threadIdx.x & 63;
    int n = blockIdx.x * 4 + wave;
    if (n >= NN) return;
    int beg = indptr[n], end = indptr[n + 1];
    int col = (lane < 50) ? lane * 2 : 0;
    float ax, ay;
    agg_core(xs, esrc, beg, end, lane, col, ax, ay);
    if (lane < 50) {
        float di = dinv[n];
        float2 xv = __half22float2(*(const __half2*)(xs + (size_t)n * LDX + col));
        float2 bv = *(const float2*)(bias + lane * 2);
        float2 r;
        r.x = fmaxf(di * (ax + 2.f * xv.x) + bv.x, 0.f);
        r.y = fmaxf(di * (ay + 2.f * xv.y) + bv.y, 0.f);
        *(float2*)(hout + (size_t)n * LDA + col) = r;
    }
}

// ---------------- pooling (8-way ILP over nodes) ----------------
__global__ __launch_bounds__(128) void k_pool(const float* __restrict__ h,
                                              const int* __restrict__ gstart,
                                              float* __restrict__ pooled) {
    int g = blockIdx.x, t = threadIdx.x;
    if (t >= 100) return;
    int st = gstart[g];
    int cnt = gstart[g + 1] - st;
    float s0 = 0.f, s1 = 0.f, s2 = 0.f, s3 = 0.f;
    float s4 = 0.f, s5 = 0.f, s6 = 0.f, s7 = 0.f;
    int i = 0;
    for (; i + 8 <= cnt; i += 8) {
        s0 += h[(size_t)(st + i) * LDA + t];
        s1 += h[(size_t)(st + i + 1) * LDA + t];
        s2 += h[(size_t)(st + i + 2) * LDA + t];
        s3 += h[(size_t)(st + i + 3) * LDA + t];
        s4 += h[(size_t)(st + i + 4) * LDA + t];
        s5 += h[(size_t)(st + i + 5) * LDA + t];
        s6 += h[(size_t)(st + i + 6) * LDA + t];
        s7 += h[(size_t)(st + i + 7) * LDA + t];
    }
    for (; i < cnt; i++) s0 += h[(size_t)(st + i) * LDA + t];
    float s = ((s0 + s1) + (s2 + s3)) + ((s4 + s5) + (s6 + s7));
    pooled[g * 100 + t] = s / (float)(cnt > 0 ? cnt : 1);
}

// ---------------- MLP head ----------------
__global__ void k_mlp(const float* __restrict__ pooled,
                      const float* __restrict__ Wl1, const float* __restrict__ bl1,
                      const float* __restrict__ Wl2, const float* __restrict__ bl2,
                      const float* __restrict__ Wl3, const float* __restrict__ bl3,
                      float* __restrict__ out) {
    __shared__ float p[100], q[100];
    int g = blockIdx.x, t = threadIdx.x;
    if (t < 100) p[t] = pooled[g * 100 + t];
    __syncthreads();
    float s1 = 0.f;
    if (t < 100) {
        s1 = bl1[t];
        for (int k = 0; k < 100; k++) s1 += p[k] * Wl1[k * 100 + t];
        s1 = fmaxf(s1, 0.f);
    }
    __syncthreads();
    if (t < 100) q[t] = s1;
    __syncthreads();
    float s2 = 0.f;
    if (t < 100) {
        s2 = bl2[t];
        for (int k = 0; k < 100; k++) s2 += q[k] * Wl2[k * 100 + t];
        s2 = fmaxf(s2, 0.f);
    }
    __syncthreads();
    if (t < 100) p[t] = s2;
    __syncthreads();
    if (t < 29) {
        float s3 = bl3[t];
        for (int k = 0; k < 100; k++) s3 += p[k] * Wl3[k * 29 + t];
        out[g * 29 + t] = s3;
    }
}

// ---------------- launch ----------------
extern "C" void kernel_launch(void* const* d_in, const int* in_sizes, int n_in,
                              void* d_out, int out_size, void* d_ws, size_t ws_size,
                              hipStream_t stream) {
    const float* x     = (const float*)d_in[0];
    const int*   ei    = (const int*)d_in[1];
    const int*   batch = (const int*)d_in[2];
    const float* W1 = (const float*)d_in[3];  const float* b1 = (const float*)d_in[4];
    const float* W2 = (const float*)d_in[5];  const float* b2 = (const float*)d_in[6];
    const float* W3 = (const float*)d_in[7];  const float* b3 = (const float*)d_in[8];
    const float* W4 = (const float*)d_in[9];  const float* b4 = (const float*)d_in[10];
    const float* W5 = (const float*)d_in[11]; const float* b5 = (const float*)d_in[12];
    const float* Wl1 = (const float*)d_in[13]; const float* bl1 = (const float*)d_in[14];
    const float* Wl2 = (const float*)d_in[15]; const float* bl2 = (const float*)d_in[16];
    const float* Wl3 = (const float*)d_in[17]; const float* bl3 = (const float*)d_in[18];
    float* out = (float*)d_out;

    const int* row = ei;
    const int* col = ei + NE;

    uintptr_t base = (uintptr_t)d_ws;
    auto alloc = [&](size_t bytes) -> void* {
        void* p = (void*)base;
        base += (bytes + 255) & ~(size_t)255;
        return p;
    };
    int*   cnts   = (int*)alloc((size_t)(2 * NN) * 4);
    int*   degcnt = cnts;
    int*   fill   = cnts + NN;
    float* dinv   = (float*)alloc(NN * 4);
    int*   indptr = (int*)alloc((NN + 1) * 4);
    int*   csum   = (int*)alloc(512 * 4);
    int*   csum2  = (int*)alloc(512 * 4);
    int*   gstart = (int*)alloc((NG + 1) * 4);
    int*   esrc   = (int*)alloc((size_t)NE * 4);
    __half* xsh   = (__half*)alloc((size_t)NN * LDX * 2);
    __half* hh    = (__half*)alloc((size_t)NN * LDX * 2);
    float* h      = (float*)alloc((size_t)NN * LDA * 4);
    float* pooled = (float*)alloc((size_t)NG * 100 * 4);
    __half* w1hi = (__half*)alloc((size_t)112 * 384 * 2);
    __half* w1lo = (__half*)alloc((size_t)112 * 384 * 2);
    __half* w2hi = (__half*)alloc((size_t)112 * 128 * 2);
    __half* w2lo = (__half*)alloc((size_t)112 * 128 * 2);
    __half* w3hi = (__half*)alloc((size_t)112 * 128 * 2);
    __half* w3lo = (__half*)alloc((size_t)112 * 128 * 2);
    __half* w4hi = (__half*)alloc((size_t)112 * 128 * 2);
    __half* w4lo = (__half*)alloc((size_t)112 * 128 * 2);
    __half* w5hi = (__half*)alloc((size_t)112 * 128 * 2);
    __half* w5lo = (__half*)alloc((size_t)112 * 128 * 2);

    hipMemsetAsync(cnts, 0, (size_t)(2 * NN) * 4, stream);

    const int NB = (NN + 255) / 256;  // 391
    k_deg<<<(NE + 255) / 256, 256, 0, stream>>>(col, degcnt);
    k_scan1<<<NB, 256, 0, stream>>>(degcnt, csum);
    k_scan2<<<1, 512, 0, stream>>>(csum, csum2, NB);
    k_scan3d<<<NB, 256, 0, stream>>>(degcnt, csum2, indptr, dinv);
    k_scatter<<<(NE + 255) / 256, 256, 0, stream>>>(row, col, indptr, fill, esrc);
    k_gbounds<<<NB, 256, 0, stream>>>(batch, gstart);
    k_convW<<<392, 256, 0, stream>>>(W1, w1hi, w1lo, W2, w2hi, w2lo,
                                     W3, w3hi, w3lo, W4, w4hi, w4lo,
                                     W5, w5hi, w5lo);

    const int GEMM_GRID = (NN + 127) / 128;  // 782
    const int AGG_GRID = (NN + 3) / 4;       // 25000

    k_gemmX<<<GEMM_GRID, 512, 0, stream>>>(x, w1hi, w1lo, dinv, xsh);
    k_aggS<<<AGG_GRID, 256, 0, stream>>>(xsh, indptr, esrc, dinv, b1, hh);
    k_gemmH<<<GEMM_GRID, 512, 0, stream>>>(hh, w2hi, w2lo, dinv, xsh);
    k_aggS<<<AGG_GRID, 256, 0, stream>>>(xsh, indptr, esrc, dinv, b2, hh);
    k_gemmH<<<GEMM_GRID, 512, 0, stream>>>(hh, w3hi, w3lo, dinv, xsh);
    k_aggS<<<AGG_GRID, 256, 0, stream>>>(xsh, indptr, esrc, dinv, b3, hh);
    k_gemmH<<<GEMM_GRID, 512, 0, stream>>>(hh, w4hi, w4lo, dinv, xsh);
    k_aggS<<<AGG_GRID, 256, 0, stream>>>(xsh, indptr, esrc, dinv, b4, hh);
    k_gemmH<<<GEMM_GRID, 512, 0, stream>>>(hh, w5hi, w5lo, dinv, xsh);
    k_agg<<<AGG_GRID, 256, 0, stream>>>(xsh, indptr, esrc, dinv, b5, h);

    k_pool<<<NG, 128, 0, stream>>>(h, gstart, pooled);
    k_mlp<<<NG, 128, 0, stream>>>(pooled, Wl1, bl1, Wl2, bl2, Wl3, bl3, out);
}

// Round 5
// 828.416 us; speedup vs baseline: 1.2412x; 1.0215x over previous
//
#include <hip/hip_runtime.h>
#include <hip/hip_fp16.h>
#include <stdint.h>

#define NN 100000
#define NE 1600000
#define NG 1000
#define LDA 112   // fp32 row stride for h (pooling input): 448 B
#define LDX 128   // half row stride for fp16 activation tables: 256 B

#define NPART 8              // XCD count; partition = blockIdx & 7
#define PRANGE 12500         // NN / NPART
#define SGRID 2048           // deg/scatter grid (256 blocks per partition)
#define PSTRIDE 65536        // (SGRID/NPART) * 256 threads

typedef float f32x4 __attribute__((ext_vector_type(4)));
typedef _Float16 f16x8 __attribute__((ext_vector_type(8)));

// async global->LDS, 16 B per lane (LDS dest = wave-uniform base + lane*16)
__device__ __forceinline__ void load_lds16(const void* g, void* l) {
    __builtin_amdgcn_global_load_lds((const __attribute__((address_space(1))) unsigned int*)g,
                                     (__attribute__((address_space(3))) unsigned int*)l,
                                     16, 0, 0);
}

// ---------------- degree (XCD-partitioned by col range) ----------------
__global__ void k_deg(const int* __restrict__ col, int* __restrict__ degcnt) {
    int part = blockIdx.x & (NPART - 1);
    int pb = blockIdx.x >> 3;
    int lo = part * PRANGE, hi = lo + PRANGE;
    for (int e = pb * 256 + threadIdx.x; e < NE; e += PSTRIDE) {
        int c = col[e];
        if (c >= lo && c < hi) atomicAdd(&degcnt[c], 1);
    }
}

// ---------------- prefix scans for CSR ----------------
__global__ void k_scan1(const int* __restrict__ cnt, int* __restrict__ csum) {
    __shared__ int s[256];
    int i = blockIdx.x * 256 + threadIdx.x;
    s[threadIdx.x] = (i < NN) ? cnt[i] : 0;
    __syncthreads();
    for (int o = 128; o > 0; o >>= 1) {
        if (threadIdx.x < o) s[threadIdx.x] += s[threadIdx.x + o];
        __syncthreads();
    }
    if (threadIdx.x == 0) csum[blockIdx.x] = s[0];
}

__global__ void k_scan2(const int* __restrict__ csum, int* __restrict__ csum2, int nb) {
    __shared__ int s[512];
    int t = threadIdx.x;
    int v = (t < nb) ? csum[t] : 0;
    s[t] = v; __syncthreads();
    for (int o = 1; o < 512; o <<= 1) {
        int x = (t >= o) ? s[t - o] : 0;
        __syncthreads();
        s[t] += x;
        __syncthreads();
    }
    if (t < nb) csum2[t] = s[t] - v;  // exclusive
}

// indptr + dinv in one pass
__global__ void k_scan3d(const int* __restrict__ cnt, const int* __restrict__ csum2,
                         int* __restrict__ indptr, float* __restrict__ dinv) {
    __shared__ int s[256];
    int t = threadIdx.x;
    int i = blockIdx.x * 256 + t;
    int v = (i < NN) ? cnt[i] : 0;
    s[t] = v; __syncthreads();
    for (int o = 1; o < 256; o <<= 1) {
        int x = (t >= o) ? s[t - o] : 0;
        __syncthreads();
        s[t] += x;
        __syncthreads();
    }
    if (i < NN) {
        indptr[i] = csum2[blockIdx.x] + s[t] - v;
        dinv[i] = 1.0f / sqrtf((float)v + 2.0f);
    }
    if (i == 0) indptr[NN] = NE;
}

// ---------------- scatter (XCD-partitioned by col range) ----------------
// Each partition's esrc writes land in one contiguous region (indptr monotone in c),
// so all dirty lines stay in a single XCD's L2 -> write-combining works.
__global__ void k_scatter(const int* __restrict__ row, const int* __restrict__ col,
                          const int* __restrict__ indptr,
                          int* __restrict__ fill, int* __restrict__ esrc) {
    int part = blockIdx.x & (NPART - 1);
    int pb = blockIdx.x >> 3;
    int lo = part * PRANGE, hi = lo + PRANGE;
    for (int e = pb * 256 + threadIdx.x; e < NE; e += PSTRIDE) {
        int c = col[e];
        int r = row[e];
        if (c >= lo && c < hi) {
            int pos = indptr[c] + atomicAdd(&fill[c], 1);
            esrc[pos] = r;
        }
    }
}

// batch is sorted: graph starts via boundary detection
__global__ void k_gbounds(const int* __restrict__ batch, int* __restrict__ gstart) {
    int i = blockIdx.x * 256 + threadIdx.x;
    if (i >= NN) return;
    int b = batch[i];
    int pb = (i == 0) ? -1 : batch[i - 1];
    for (int g = pb + 1; g <= b; g++) gstart[g] = i;
    if (i == NN - 1) {
        for (int g = b + 1; g <= NG; g++) gstart[g] = NN;
    }
}

// ----- weight conversion: split-fp16, Wt[n][k], lo scaled by 2048 -----
// Stored PRE-SWIZZLED: within each 128-half row-chunk, half-col k -> k ^ ((n&7)<<3)
// (byte-swizzle ((n&7)<<4)). LDS staging is then a linear copy; LDS reads use the
// same XOR -> low-conflict ds_read_b128.
__global__ void k_convW(const float* __restrict__ W1, __half* __restrict__ w1h, __half* __restrict__ w1l,
                        const float* __restrict__ W2, __half* __restrict__ w2h, __half* __restrict__ w2l,
                        const float* __restrict__ W3, __half* __restrict__ w3h, __half* __restrict__ w3l,
                        const float* __restrict__ W4, __half* __restrict__ w4h, __half* __restrict__ w4l,
                        const float* __restrict__ W5, __half* __restrict__ w5h, __half* __restrict__ w5l) {
    int b = blockIdx.x, t = threadIdx.x;
    const float* W; __half *Wh, *Wl; int K, KCP, idx;
    if (b < 168) {            // layer 1: 112*384 = 43008 = 168 blocks
        W = W1; Wh = w1h; Wl = w1l; K = 336; KCP = 384; idx = b * 256 + t;
    } else {                  // layers 2..5: 112*128 = 14336 = 56 blocks each
        int li = (b - 168) / 56;
        int lb = (b - 168) % 56;
        const float* Ws[4] = {W2, W3, W4, W5};
        __half* Whs[4] = {w2h, w3h, w4h, w5h};
        __half* Wls[4] = {w2l, w3l, w4l, w5l};
        W = Ws[li]; Wh = Whs[li]; Wl = Wls[li]; K = 100; KCP = 128; idx = lb * 256 + t;
    }
    int n = idx / KCP, k = idx - n * KCP;
    float v = (n < 100 && k < K) ? W[k * 100 + n] : 0.f;
    __half hi = __float2half(v);
    __half lo = __float2half((v - __half2float(hi)) * 2048.f);
    int kc = k & 127;
    size_t so = (size_t)n * KCP + (k - kc) + (kc ^ ((n & 7) << 3));
    Wh[so] = hi;
    Wl[so] = lo;
}

__device__ __forceinline__ f16x8 cvt8(float4 v0, float4 v1) {
    __half2 p0 = __floats2half2_rn(v0.x, v0.y);
    __half2 p1 = __floats2half2_rn(v0.z, v0.w);
    __half2 p2 = __floats2half2_rn(v1.x, v1.y);
    __half2 p3 = __floats2half2_rn(v1.z, v1.w);
    union { uint4 u; f16x8 f; } c;
    c.u.x = __builtin_bit_cast(unsigned, p0);
    c.u.y = __builtin_bit_cast(unsigned, p1);
    c.u.z = __builtin_bit_cast(unsigned, p2);
    c.u.w = __builtin_bit_cast(unsigned, p3);
    return c.f;
}

// ---- layer-1 GEMM: 512 thr / 8 waves / 128 rows; W chunk staged in LDS ----
__global__ __launch_bounds__(512, 4) void k_gemmX(const float* __restrict__ x,
                                                  const __half* __restrict__ Whi,
                                                  const __half* __restrict__ Wlo,
                                                  const float* __restrict__ dinv,
                                                  __half* __restrict__ out) {
    __shared__ __align__(16) __half Hs[112 * 128];
    __shared__ __align__(16) __half Ls[112 * 128];
    int t = threadIdx.x;
    int lane = t & 63, wv = t >> 6;
    int l15 = lane & 15, quad = lane >> 4;
    int rowbase = blockIdx.x * 128;
    int arow = rowbase + wv * 16 + l15;

    f32x4 acch[7], accl[7];
#pragma unroll
    for (int i = 0; i < 7; i++)
#pragma unroll
        for (int r = 0; r < 4; r++) { acch[i][r] = 0.f; accl[i][r] = 0.f; }

    int swz = (l15 & 7) << 4;

    for (int k0 = 0; k0 < 384; k0 += 128) {
        // A frags for this chunk: global loads, no LDS hazard -> issue BEFORE the
        // inter-chunk barrier so their latency hides under the previous MFMA drain.
        f16x8 a[4];
#pragma unroll
        for (int ks = 0; ks < 4; ks++) {
            int k = k0 + ks * 32 + quad * 8;
            float4 v0 = make_float4(0.f, 0.f, 0.f, 0.f), v1 = v0;
            if (arow < NN && k < 336) {
                const float* p = x + (size_t)arow * 336 + k;
                v0 = *(const float4*)p;
                v1 = *(const float4*)(p + 4);
            }
            a[ks] = cvt8(v0, v1);
        }
        if (k0) __syncthreads();
        // stage W chunk [112][128] hi+lo: 56 wave-chunks of 1 KB (wave-uniform table pick)
#pragma unroll
        for (int cch = 0; cch < 7; cch++) {
            int g = wv + cch * 8;          // 0..55, uniform per wave
            int tb = (g >= 28);
            int o = (g - (tb ? 28 : 0)) * 1024 + lane * 16;
            int r = o >> 8, cc = o & 255;
            size_t src = (size_t)r * 768 + (size_t)(k0 * 2) + cc;
            if (!tb) load_lds16((const char*)Whi + src, (char*)Hs + o);
            else     load_lds16((const char*)Wlo + src, (char*)Ls + o);
        }
        __syncthreads();
#pragma unroll
        for (int ks = 0; ks < 4; ks++) {
            int cb = (ks * 64 + quad * 16) ^ swz;
#pragma unroll
            for (int tt = 0; tt < 7; tt++) {
                int ro = (tt * 16 + l15) * 256;
                f16x8 bh = *(const f16x8*)((const char*)Hs + ro + cb);
                f16x8 bl = *(const f16x8*)((const char*)Ls + ro + cb);
                acch[tt] = __builtin_amdgcn_mfma_f32_16x16x32_f16(a[ks], bh, acch[tt], 0, 0, 0);
                accl[tt] = __builtin_amdgcn_mfma_f32_16x16x32_f16(a[ks], bl, accl[tt], 0, 0, 0);
            }
        }
    }

    int gr0 = rowbase + wv * 16 + quad * 4;
    float dv[4];
#pragma unroll
    for (int reg = 0; reg < 4; reg++) dv[reg] = (gr0 + reg < NN) ? dinv[gr0 + reg] : 0.f;
#pragma unroll
    for (int tt = 0; tt < 7; tt++) {
        int n = tt * 16 + l15;
#pragma unroll
        for (int reg = 0; reg < 4; reg++) {
            int gr = gr0 + reg;
            if (gr < NN)
                out[(size_t)gr * LDX + n] =
                    __float2half(dv[reg] * (acch[tt][reg] + accl[tt][reg] * (1.f / 2048.f)));
        }
    }
    if (l15 < 8) {  // zero k-pad cols 112..127 so next layer's A-frags are clean
#pragma unroll
        for (int reg = 0; reg < 4; reg++) {
            int gr = gr0 + reg;
            if (gr < NN) *(unsigned int*)(out + (size_t)gr * LDX + 112 + l15 * 2) = 0u;
        }
    }
}

// ---- layers 2-5 GEMM: 512 thr / 8 waves / 128 rows; full W in LDS, 1 barrier ----
__global__ __launch_bounds__(512, 4) void k_gemmH(const __half* __restrict__ act,
                                                  const __half* __restrict__ Whi,
                                                  const __half* __restrict__ Wlo,
                                                  const float* __restrict__ dinv,
                                                  __half* __restrict__ out) {
    __shared__ __align__(16) __half Hs[112 * 128];
    __shared__ __align__(16) __half Ls[112 * 128];
    int t = threadIdx.x;
    int lane = t & 63, wv = t >> 6;
    int l15 = lane & 15, quad = lane >> 4;
    int rowbase = blockIdx.x * 128;
    int ar = min(rowbase + wv * 16 + l15, NN - 1);  // clamp: results discarded

    // A frags: 4 x 16 B per lane, issued before the W DMA (latency overlaps)
    const char* ap = (const char*)act + (size_t)ar * 256;
    f16x8 a[4];
#pragma unroll
    for (int ks = 0; ks < 4; ks++)
        a[ks] = *(const f16x8*)(ap + ks * 64 + quad * 16);

    // stage full W [112][128] hi+lo (pre-swizzled, linear copy)
#pragma unroll
    for (int cch = 0; cch < 7; cch++) {
        int g = wv + cch * 8;
        int tb = (g >= 28);
        int o = (g - (tb ? 28 : 0)) * 1024 + lane * 16;
        if (!tb) load_lds16((const char*)Whi + o, (char*)Hs + o);
        else     load_lds16((const char*)Wlo + o, (char*)Ls + o);
    }

    f32x4 acch[7], accl[7];
#pragma unroll
    for (int i = 0; i < 7; i++)
#pragma unroll
        for (int r = 0; r < 4; r++) { acch[i][r] = 0.f; accl[i][r] = 0.f; }

    __syncthreads();
    int swz = (l15 & 7) << 4;
#pragma unroll
    for (int ks = 0; ks < 4; ks++) {
        int cb = (ks * 64 + quad * 16) ^ swz;
#pragma unroll
        for (int tt = 0; tt < 7; tt++) {
            int ro = (tt * 16 + l15) * 256;
            f16x8 bh = *(const f16x8*)((const char*)Hs + ro + cb);
            f16x8 bl = *(const f16x8*)((const char*)Ls + ro + cb);
            acch[tt] = __builtin_amdgcn_mfma_f32_16x16x32_f16(a[ks], bh, acch[tt], 0, 0, 0);
            accl[tt] = __builtin_amdgcn_mfma_f32_16x16x32_f16(a[ks], bl, accl[tt], 0, 0, 0);
        }
    }

    int gr0 = rowbase + wv * 16 + quad * 4;
    float dv[4];
#pragma unroll
    for (int reg = 0; reg < 4; reg++) dv[reg] = (gr0 + reg < NN) ? dinv[gr0 + reg] : 0.f;
#pragma unroll
    for (int tt = 0; tt < 7; tt++) {
        int n = tt * 16 + l15;
#pragma unroll
        for (int reg = 0; reg < 4; reg++) {
            int gr = gr0 + reg;
            if (gr < NN)
                out[(size_t)gr * LDX + n] =
                    __float2half(dv[reg] * (acch[tt][reg] + accl[tt][reg] * (1.f / 2048.f)));
        }
    }
    if (l15 < 8) {
#pragma unroll
        for (int reg = 0; reg < 4; reg++) {
            int gr = gr0 + reg;
            if (gr < NN) *(unsigned int*)(out + (size_t)gr * LDX + 112 + l15 * 2) = 0u;
        }
    }
}

// ---- aggregation core: gathers fp16 rows (4 cache lines/row), fp32 accumulate ----
__device__ __forceinline__ void agg_core(const __half* __restrict__ xs,
                                         const int* __restrict__ esrc,
                                         int beg, int end, int lane, int col,
                                         float& ax, float& ay) {
    ax = 0.f; ay = 0.f;
    for (int c = beg; c < end; c += 64) {
        int m = min(64, end - c);
        int se = 0;
        if (lane < m) se = esrc[c + lane];
        int j = 0;
        for (; j + 16 <= m; j += 16) {
            __half2 v[16];
#pragma unroll
            for (int u = 0; u < 16; u++) {
                int s = __builtin_amdgcn_readlane(se, j + u);
                v[u] = *(const __half2*)(xs + (size_t)s * LDX + col);
            }
#pragma unroll
            for (int u = 0; u < 16; u++) {
                float2 f = __half22float2(v[u]);
                ax += f.x; ay += f.y;
            }
        }
        for (; j + 8 <= m; j += 8) {
            __half2 v[8];
#pragma unroll
            for (int u = 0; u < 8; u++) {
                int s = __builtin_amdgcn_readlane(se, j + u);
                v[u] = *(const __half2*)(xs + (size_t)s * LDX + col);
            }
#pragma unroll
            for (int u = 0; u < 8; u++) {
                float2 f = __half22float2(v[u]);
                ax += f.x; ay += f.y;
            }
        }
        for (; j + 4 <= m; j += 4) {
            __half2 v[4];
#pragma unroll
            for (int u = 0; u < 4; u++) {
                int s = __builtin_amdgcn_readlane(se, j + u);
                v[u] = *(const __half2*)(xs + (size_t)s * LDX + col);
            }
#pragma unroll
            for (int u = 0; u < 4; u++) {
                float2 f = __half22float2(v[u]);
                ax += f.x; ay += f.y;
            }
        }
        for (; j < m; j++) {
            int s = __builtin_amdgcn_readlane(se, j);
            float2 f = __half22float2(*(const __half2*)(xs + (size_t)s * LDX + col));
            ax += f.x; ay += f.y;
        }
    }
}

// ---- agg, layers 1-4: writes single fp16 activation table (128-stride, padded) ----
__global__ __launch_bounds__(256) void k_aggS(const __half* __restrict__ xs,
                                              const int* __restrict__ indptr,
                                              const int* __restrict__ esrc,
                                              const float* __restrict__ dinv,
                                              const float* __restrict__ bias,
                                              __half* __restrict__ hh) {
    int wave = threadIdx.x >> 6;
    int lane = threadIdx.x & 63;
    int n = blockIdx.x * 4 + wave;
    if (n >= NN) return;
    int beg = indptr[n], end = indptr[n + 1];
    int col = (lane < 50) ? lane * 2 : 0;
    float ax, ay;
    agg_core(xs, esrc, beg, end, lane, col, ax, ay);
    if (lane < 50) {
        float di = dinv[n];
        float2 xv = __half22float2(*(const __half2*)(xs + (size_t)n * LDX + col));
        float2 bv = *(const float2*)(bias + lane * 2);
        float hx = fmaxf(di * (ax + 2.f * xv.x) + bv.x, 0.f);
        float hy = fmaxf(di * (ay + 2.f * xv.y) + bv.y, 0.f);
        *(__half2*)(hh + (size_t)n * LDX + col) = __floats2half2_rn(hx, hy);
    } else {
        int pc = 100 + (lane - 50) * 2;  // zero pad cols 100..127
        *(unsigned int*)(hh + (size_t)n * LDX + pc) = 0u;
    }
}

// ---- agg, layer 5: fp32 epilogue for pooling ----
__global__ __launch_bounds__(256) void k_agg(const __half* __restrict__ xs,
                                             const int* __restrict__ indptr,
                                             const int* __restrict__ esrc,
                                             const float* __restrict__ dinv,
                                             const float* __restrict__ bias,
                                             float* __restrict__ hout) {
    int wave = threadIdx.x >> 6;
    int lane = threadIdx.x & 63;
    int n = blockIdx.x * 4 + wave;
    if (n >= NN) return;
    int beg = indptr[n], end = indptr[n + 1];
    int col = (lane < 50) ? lane * 2 : 0;
    float ax, ay;
    agg_core(xs, esrc, beg, end, lane, col, ax, ay);
    if (lane < 50) {
        float di = dinv[n];
        float2 xv = __half22float2(*(const __half2*)(xs + (size_t)n * LDX + col));
        float2 bv = *(const float2*)(bias + lane * 2);
        float2 r;
        r.x = fmaxf(di * (ax + 2.f * xv.x) + bv.x, 0.f);
        r.y = fmaxf(di * (ay + 2.f * xv.y) + bv.y, 0.f);
        *(float2*)(hout + (size_t)n * LDA + col) = r;
    }
}

// ---------------- pooling (8-way ILP over nodes) ----------------
__global__ __launch_bounds__(128) void k_pool(const float* __restrict__ h,
                                              const int* __restrict__ gstart,
                                              float* __restrict__ pooled) {
    int g = blockIdx.x, t = threadIdx.x;
    if (t >= 100) return;
    int st = gstart[g];
    int cnt = gstart[g + 1] - st;
    float s0 = 0.f, s1 = 0.f, s2 = 0.f, s3 = 0.f;
    float s4 = 0.f, s5 = 0.f, s6 = 0.f, s7 = 0.f;
    int i = 0;
    for (; i + 8 <= cnt; i += 8) {
        s0 += h[(size_t)(st + i) * LDA + t];
        s1 += h[(size_t)(st + i + 1) * LDA + t];
        s2 += h[(size_t)(st + i + 2) * LDA + t];
        s3 += h[(size_t)(st + i + 3) * LDA + t];
        s4 += h[(size_t)(st + i + 4) * LDA + t];
        s5 += h[(size_t)(st + i + 5) * LDA + t];
        s6 += h[(size_t)(st + i + 6) * LDA + t];
        s7 += h[(size_t)(st + i + 7) * LDA + t];
    }
    for (; i < cnt; i++) s0 += h[(size_t)(st + i) * LDA + t];
    float s = ((s0 + s1) + (s2 + s3)) + ((s4 + s5) + (s6 + s7));
    pooled[g * 100 + t] = s / (float)(cnt > 0 ? cnt : 1);
}

// ---------------- MLP head ----------------
__global__ void k_mlp(const float* __restrict__ pooled,
                      const float* __restrict__ Wl1, const float* __restrict__ bl1,
                      const float* __restrict__ Wl2, const float* __restrict__ bl2,
                      const float* __restrict__ Wl3, const float* __restrict__ bl3,
                      float* __restrict__ out) {
    __shared__ float p[100], q[100];
    int g = blockIdx.x, t = threadIdx.x;
    if (t < 100) p[t] = pooled[g * 100 + t];
    __syncthreads();
    float s1 = 0.f;
    if (t < 100) {
        s1 = bl1[t];
        for (int k = 0; k < 100; k++) s1 += p[k] * Wl1[k * 100 + t];
        s1 = fmaxf(s1, 0.f);
    }
    __syncthreads();
    if (t < 100) q[t] = s1;
    __syncthreads();
    float s2 = 0.f;
    if (t < 100) {
        s2 = bl2[t];
        for (int k = 0; k < 100; k++) s2 += q[k] * Wl2[k * 100 + t];
        s2 = fmaxf(s2, 0.f);
    }
    __syncthreads();
    if (t < 100) p[t] = s2;
    __syncthreads();
    if (t < 29) {
        float s3 = bl3[t];
        for (int k = 0; k < 100; k++) s3 += p[k] * Wl3[k * 29 + t];
        out[g * 29 + t] = s3;
    }
}

// ---------------- launch ----------------
extern "C" void kernel_launch(void* const* d_in, const int* in_sizes, int n_in,
                              void* d_out, int out_size, void* d_ws, size_t ws_size,
                              hipStream_t stream) {
    const float* x     = (const float*)d_in[0];
    const int*   ei    = (const int*)d_in[1];
    const int*   batch = (const int*)d_in[2];
    const float* W1 = (const float*)d_in[3];  const float* b1 = (const float*)d_in[4];
    const float* W2 = (const float*)d_in[5];  const float* b2 = (const float*)d_in[6];
    const float* W3 = (const float*)d_in[7];  const float* b3 = (const float*)d_in[8];
    const float* W4 = (const float*)d_in[9];  const float* b4 = (const float*)d_in[10];
    const float* W5 = (const float*)d_in[11]; const float* b5 = (const float*)d_in[12];
    const float* Wl1 = (const float*)d_in[13]; const float* bl1 = (const float*)d_in[14];
    const float* Wl2 = (const float*)d_in[15]; const float* bl2 = (const float*)d_in[16];
    const float* Wl3 = (const float*)d_in[17]; const float* bl3 = (const float*)d_in[18];
    float* out = (float*)d_out;

    const int* row = ei;
    const int* col = ei + NE;

    uintptr_t base = (uintptr_t)d_ws;
    auto alloc = [&](size_t bytes) -> void* {
        void* p = (void*)base;
        base += (bytes + 255) & ~(size_t)255;
        return p;
    };
    int*   cnts   = (int*)alloc((size_t)(2 * NN) * 4);
    int*   degcnt = cnts;
    int*   fill   = cnts + NN;
    float* dinv   = (float*)alloc(NN * 4);
    int*   indptr = (int*)alloc((NN + 1) * 4);
    int*   csum   = (int*)alloc(512 * 4);
    int*   csum2  = (int*)alloc(512 * 4);
    int*   gstart = (int*)alloc((NG + 1) * 4);
    int*   esrc   = (int*)alloc((size_t)NE * 4);
    __half* xsh   = (__half*)alloc((size_t)NN * LDX * 2);
    __half* hh    = (__half*)alloc((size_t)NN * LDX * 2);
    float* h      = (float*)alloc((size_t)NN * LDA * 4);
    float* pooled = (float*)alloc((size_t)NG * 100 * 4);
    __half* w1hi = (__half*)alloc((size_t)112 * 384 * 2);
    __half* w1lo = (__half*)alloc((size_t)112 * 384 * 2);
    __half* w2hi = (__half*)alloc((size_t)112 * 128 * 2);
    __half* w2lo = (__half*)alloc((size_t)112 * 128 * 2);
    __half* w3hi = (__half*)alloc((size_t)112 * 128 * 2);
    __half* w3lo = (__half*)alloc((size_t)112 * 128 * 2);
    __half* w4hi = (__half*)alloc((size_t)112 * 128 * 2);
    __half* w4lo = (__half*)alloc((size_t)112 * 128 * 2);
    __half* w5hi = (__half*)alloc((size_t)112 * 128 * 2);
    __half* w5lo = (__half*)alloc((size_t)112 * 128 * 2);

    hipMemsetAsync(cnts, 0, (size_t)(2 * NN) * 4, stream);

    const int NB = (NN + 255) / 256;  // 391
    k_deg<<<SGRID, 256, 0, stream>>>(col, degcnt);
    k_scan1<<<NB, 256, 0, stream>>>(degcnt, csum);
    k_scan2<<<1, 512, 0, stream>>>(csum, csum2, NB);
    k_scan3d<<<NB, 256, 0, stream>>>(degcnt, csum2, indptr, dinv);
    k_scatter<<<SGRID, 256, 0, stream>>>(row, col, indptr, fill, esrc);
    k_gbounds<<<NB, 256, 0, stream>>>(batch, gstart);
    k_convW<<<392, 256, 0, stream>>>(W1, w1hi, w1lo, W2, w2hi, w2lo,
                                     W3, w3hi, w3lo, W4, w4hi, w4lo,
                                     W5, w5hi, w5lo);

    const int GEMM_GRID = (NN + 127) / 128;  // 782
    const int AGG_GRID = (NN + 3) / 4;       // 25000

    k_gemmX<<<GEMM_GRID, 512, 0, stream>>>(x, w1hi, w1lo, dinv, xsh);
    k_aggS<<<AGG_GRID, 256, 0, stream>>>(xsh, indptr, esrc, dinv, b1, hh);
    k_gemmH<<<GEMM_GRID, 512, 0, stream>>>(hh, w2hi, w2lo, dinv, xsh);
    k_aggS<<<AGG_GRID, 256, 0, stream>>>(xsh, indptr, esrc, dinv, b2, hh);
    k_gemmH<<<GEMM_GRID, 512, 0, stream>>>(hh, w3hi, w3lo, dinv, xsh);
    k_aggS<<<AGG_GRID, 256, 0, stream>>>(xsh, indptr, esrc, dinv, b3, hh);
    k_gemmH<<<GEMM_GRID, 512, 0, stream>>>(hh, w4hi, w4lo, dinv, xsh);
    k_aggS<<<AGG_GRID, 256, 0, stream>>>(xsh, indptr, esrc, dinv, b4, hh);
    k_gemmH<<<GEMM_GRID, 512, 0, stream>>>(hh, w5hi, w5lo, dinv, xsh);
    k_agg<<<AGG_GRID, 256, 0, stream>>>(xsh, indptr, esrc, dinv, b5, h);

    k_pool<<<NG, 128, 0, stream>>>(h, gstart, pooled);
    k_mlp<<<NG, 128, 0, stream>>>(pooled, Wl1, bl1, Wl2, bl2, Wl3, bl3, out);
}